// Round 7
// baseline (88.068 us; speedup 1.0000x reference)
//
#include <hip/hip_runtime.h>
#include <hip/hip_bf16.h>
#include <math.h>

// Problem constants
#define BB   2
#define NN   2048
#define DIMM 512
#define HH   8
#define NC3  1536
#define BN   4096

typedef __attribute__((ext_vector_type(8))) short short8;
typedef __attribute__((ext_vector_type(4))) float f32x4;
typedef unsigned short u16t;

__device__ inline short bfc(float f) {
    __hip_bfloat16 h = __float2bfloat16(f);
    return *reinterpret_cast<short*>(&h);
}
__device__ inline float bf2f(u16t u) {
    return __uint_as_float(((unsigned)u) << 16);
}

// XOR-swizzle of 16B granules within [rows x 64B] LDS tiles (involution,
// applied on BOTH ds_write and ds_read sides — R3-proven mapping).
#define SWZ(P) ((P) ^ ((((P) >> 7) & 3) << 4))

// ---------------------------------------------------------------------------
// qkv GEMM (R3-proven): QKV[4096x1536](bf16) = x[4096x512](f32) @ w_qkv^T(f32)
// fp32->bf16 conversion fused into staging. 128x128 tile, BK=32, 4 waves 2x2.
// Also zeroes the 16 sync counters used by mpartf.
// ---------------------------------------------------------------------------
__global__ __launch_bounds__(256) void qkvgemm(
    const float* __restrict__ A, const float* __restrict__ Bw,
    u16t* __restrict__ QKV, unsigned* __restrict__ ctr)
{
    __shared__ __align__(16) char smem[16384];   // A [0,8K), B [8K,16K)

    const int tid  = threadIdx.x;
    const int wave = tid >> 6, lane = tid & 63;
    const int wr = wave >> 1, wc = wave & 1;

    // XCD-aware bijective swizzle (nwg = 384, 384/8 = 48)
    int bid = blockIdx.y * gridDim.x + blockIdx.x;
    if (bid == 0 && tid < 16) ctr[tid] = 0;      // reset mpartf counters
    int swz = (bid & 7) * 48 + (bid >> 3);
    const int row0 = (swz & 31) * 128;           // gridDim.x == 32
    const int c0   = (swz >> 5) * 128;

    float4 ra[2][2], rb[2][2];

#define QLOAD(KT) {                                                           \
    _Pragma("unroll")                                                         \
    for (int it = 0; it < 2; ++it) {                                          \
        int c = tid + it * 256, r = c >> 2, g = c & 3;                        \
        const float* pa = A + (size_t)(row0 + r) * DIMM + (KT) + g * 8;       \
        ra[it][0] = *(const float4*)pa; ra[it][1] = *(const float4*)(pa + 4); \
        const float* pb = Bw + (size_t)(c0 + r) * DIMM + (KT) + g * 8;        \
        rb[it][0] = *(const float4*)pb; rb[it][1] = *(const float4*)(pb + 4); \
    } }

#define QWRITE() {                                                            \
    _Pragma("unroll")                                                         \
    for (int it = 0; it < 2; ++it) {                                          \
        int P = (tid + it * 256) * 16;                                        \
        short8 av, bv;                                                        \
        av[0]=bfc(ra[it][0].x); av[1]=bfc(ra[it][0].y);                       \
        av[2]=bfc(ra[it][0].z); av[3]=bfc(ra[it][0].w);                       \
        av[4]=bfc(ra[it][1].x); av[5]=bfc(ra[it][1].y);                       \
        av[6]=bfc(ra[it][1].z); av[7]=bfc(ra[it][1].w);                       \
        bv[0]=bfc(rb[it][0].x); bv[1]=bfc(rb[it][0].y);                       \
        bv[2]=bfc(rb[it][0].z); bv[3]=bfc(rb[it][0].w);                       \
        bv[4]=bfc(rb[it][1].x); bv[5]=bfc(rb[it][1].y);                       \
        bv[6]=bfc(rb[it][1].z); bv[7]=bfc(rb[it][1].w);                       \
        *(short8*)(smem + SWZ(P)) = av;                                       \
        *(short8*)(smem + 8192 + SWZ(P)) = bv;                                \
    } }

    // per-lane swizzled read offsets (loop-invariant)
    int rdA[4], rdB[4];
#pragma unroll
    for (int i = 0; i < 4; ++i) {
        int Pa = (wr * 64 + i * 16 + (lane & 15)) * 64 + (lane >> 4) * 16;
        rdA[i] = SWZ(Pa);
        int Pb = (wc * 64 + i * 16 + (lane & 15)) * 64 + (lane >> 4) * 16;
        rdB[i] = 8192 + SWZ(Pb);
    }

    f32x4 acc[4][4];
#pragma unroll
    for (int i = 0; i < 4; ++i)
#pragma unroll
        for (int j = 0; j < 4; ++j) acc[i][j] = (f32x4){0.f, 0.f, 0.f, 0.f};

    QLOAD(0);
    for (int kt = 0; kt < DIMM; kt += 32) {
        QWRITE();
        __syncthreads();
        if (kt + 32 < DIMM) QLOAD(kt + 32);

        short8 af[4], bfr[4];
#pragma unroll
        for (int i = 0; i < 4; ++i) {
            af[i]  = *(const short8*)(smem + rdA[i]);
            bfr[i] = *(const short8*)(smem + rdB[i]);
        }
#pragma unroll
        for (int i = 0; i < 4; ++i)
#pragma unroll
            for (int j = 0; j < 4; ++j)
                acc[i][j] = __builtin_amdgcn_mfma_f32_16x16x32_bf16(
                    af[i], bfr[j], acc[i][j], 0, 0, 0);
        __syncthreads();
    }
#undef QLOAD
#undef QWRITE

    // epilogue: bf16 row-major. C/D: col = lane&15, row = (lane>>4)*4 + reg
#pragma unroll
    for (int j = 0; j < 4; ++j) {
        int col = c0 + wc * 64 + j * 16 + (lane & 15);
#pragma unroll
        for (int i = 0; i < 4; ++i) {
#pragma unroll
            for (int r = 0; r < 4; ++r) {
                int row = row0 + wr * 64 + i * 16 + (lane >> 4) * 4 + r;
                QKV[(size_t)row * NC3 + col] = (u16t)bfc(acc[i][j][r]);
            }
        }
    }
}

// ---------------------------------------------------------------------------
// mpartf: fused Mpart producers + Mfinal consumers (one launch).
//   Producers (bid < 512): (bh, chunk of 64 rows).
//     qs[r][e] = softmax_e(Q) via no-max exp (mathematically identical; |q|<~6
//     so exp is fp32-safe). Lane owns 8 dims of one row: short8 load, 8 exp,
//     3-step shfl_xor over the 8 lanes sharing the row.
//     ks[r][d] = exp(K). Then Mp[d][e] = sum_r ks*qs (4x4 micro-tile) and
//     per-chunk column sums ksump[d]; release-increment ctr[bh].
//   Consumers (bid >= 512): (bh, ot); spin on ctr[bh]==32 (acquire), then
//     reduce Mp -> M (normalize by sum ksump) and fold into w_out:
//     W2T[b][o][h*64+d] = sum_e M[d][e] * w_out[o][h*64+e]  (bf16).
//   All 576 blocks are co-resident (LDS 34KB -> 4 blocks/CU) => no deadlock.
// ---------------------------------------------------------------------------
__global__ __launch_bounds__(256) void mpartf(
    const u16t* __restrict__ QKV, float* __restrict__ Mp,
    float* __restrict__ ksump, const float* __restrict__ w_out,
    u16t* __restrict__ W2T, unsigned* __restrict__ ctr)
{
    __shared__ __align__(16) char sh[34048];

    const int bid = blockIdx.x;
    const int tid = threadIdx.x;

    if (bid < 512) {
        // ---------------- producer ----------------
        float (*qs)[64] = (float(*)[64])sh;             // 16KB
        float (*ks)[64] = (float(*)[64])(sh + 16384);   // 16KB

        int bh = bid >> 5, ch = bid & 31;
        int b = bh >> 3, h = bh & 7;
        int w = tid >> 6, l = tid & 63;
        const u16t* Qb = QKV + ((size_t)b * NN + ch * 64) * NC3 + h * 64;
        const u16t* Kb = Qb + 512;

        const int rr = w * 16 + (l >> 3);
        const int d0 = (l & 7) * 8;
#pragma unroll
        for (int it = 0; it < 2; ++it) {
            int r = rr + it * 8;
            short8 qv = *(const short8*)(Qb + (size_t)r * NC3 + d0);
            float e[8]; float s = 0.f;
#pragma unroll
            for (int u = 0; u < 8; ++u) { e[u] = __expf(bf2f((u16t)qv[u])); s += e[u]; }
            s += __shfl_xor(s, 1); s += __shfl_xor(s, 2); s += __shfl_xor(s, 4);
            float inv = 1.0f / s;
            f32x4 v0 = {e[0]*inv, e[1]*inv, e[2]*inv, e[3]*inv};
            f32x4 v1 = {e[4]*inv, e[5]*inv, e[6]*inv, e[7]*inv};
            *(f32x4*)&qs[r][d0] = v0; *(f32x4*)&qs[r][d0 + 4] = v1;

            short8 kv = *(const short8*)(Kb + (size_t)r * NC3 + d0);
            f32x4 k0, k1;
#pragma unroll
            for (int u = 0; u < 4; ++u) k0[u] = __expf(bf2f((u16t)kv[u]));
#pragma unroll
            for (int u = 0; u < 4; ++u) k1[u] = __expf(bf2f((u16t)kv[u + 4]));
            *(f32x4*)&ks[r][d0] = k0; *(f32x4*)&ks[r][d0 + 4] = k1;
        }
        __syncthreads();

        int tx = tid & 15, ty = tid >> 4;
        float acc[4][4];
#pragma unroll
        for (int i = 0; i < 4; ++i)
#pragma unroll
            for (int j = 0; j < 4; ++j) acc[i][j] = 0.f;

#pragma unroll 8
        for (int r = 0; r < 64; ++r) {
            float4 a = *(const float4*)&ks[r][ty * 4];
            float4 q4 = *(const float4*)&qs[r][tx * 4];
            acc[0][0] += a.x * q4.x; acc[0][1] += a.x * q4.y;
            acc[0][2] += a.x * q4.z; acc[0][3] += a.x * q4.w;
            acc[1][0] += a.y * q4.x; acc[1][1] += a.y * q4.y;
            acc[1][2] += a.y * q4.z; acc[1][3] += a.y * q4.w;
            acc[2][0] += a.z * q4.x; acc[2][1] += a.z * q4.y;
            acc[2][2] += a.z * q4.z; acc[2][3] += a.z * q4.w;
            acc[3][0] += a.w * q4.x; acc[3][1] += a.w * q4.y;
            acc[3][2] += a.w * q4.z; acc[3][3] += a.w * q4.w;
        }

        float* mp = Mp + ((size_t)(bh * 32 + ch)) * 4096;
#pragma unroll
        for (int i = 0; i < 4; ++i)
            *(float4*)(mp + (ty * 4 + i) * 64 + tx * 4) =
                make_float4(acc[i][0], acc[i][1], acc[i][2], acc[i][3]);

        if (tid < 64) {
            float s = 0.f;
            for (int r = 0; r < 64; ++r) s += ks[r][tid];
            ksump[(bh * 32 + ch) * 64 + tid] = s;
        }
        __syncthreads();   // all global stores retired (vmcnt drained)
        if (tid == 0)
            __hip_atomic_fetch_add(&ctr[bh], 1u, __ATOMIC_RELEASE,
                                   __HIP_MEMORY_SCOPE_AGENT);
    } else {
        // ---------------- consumer (mfinal) ----------------
        float* kst       = (float*)sh;                        // 256B
        float (*Ms)[68]  = (float(*)[68])(sh + 256);          // 17408B
        float (*Wt)[64]  = (float(*)[64])(sh + 256 + 17408);  // 16384B

        int idx4 = bid - 512;
        int bh = idx4 >> 2, ot = idx4 & 3;
        int b = bh >> 3, h = bh & 7;
        int d = tid & 63, og = tid >> 6;

        if (tid == 0) {
            while (__hip_atomic_load(&ctr[bh], __ATOMIC_ACQUIRE,
                                     __HIP_MEMORY_SCOPE_AGENT) != 32u)
                __builtin_amdgcn_s_sleep(8);
        }
        __syncthreads();

        if (tid < 64) {
            float s = 0.f;
            for (int c = 0; c < 32; ++c) s += ksump[(bh * 32 + c) * 64 + tid];
            kst[tid] = s;
        }
        __syncthreads();

        for (int idx = tid; idx < 4096; idx += 256) {
            float s = 0.f;
            for (int c = 0; c < 32; ++c)
                s += Mp[((size_t)(bh * 32 + c)) * 4096 + idx];
            Ms[idx >> 6][idx & 63] = s / kst[idx >> 6];
        }
        __syncthreads();

        float Mreg[64];
#pragma unroll
        for (int e4 = 0; e4 < 16; ++e4) {
            float4 v = *(const float4*)&Ms[d][e4 * 4];
            Mreg[e4 * 4 + 0] = v.x; Mreg[e4 * 4 + 1] = v.y;
            Mreg[e4 * 4 + 2] = v.z; Mreg[e4 * 4 + 3] = v.w;
        }

        for (int sub = 0; sub < 2; ++sub) {
            int ob = ot * 128 + sub * 64;
            __syncthreads();
            {
                int o = tid >> 2, e0 = (tid & 3) * 16;
#pragma unroll
                for (int q = 0; q < 4; ++q)
                    *(float4*)&Wt[o][e0 + q * 4] =
                        *(const float4*)&w_out[(size_t)(ob + o) * DIMM + h * 64 + e0 + q * 4];
            }
            __syncthreads();
#pragma unroll
            for (int oo = 0; oo < 16; ++oo) {
                int o = og * 16 + oo;
                float a = 0.f;
#pragma unroll
                for (int e4 = 0; e4 < 16; ++e4) {
                    float4 wv = *(const float4*)&Wt[o][e4 * 4];
                    a += wv.x * Mreg[e4 * 4 + 0] + wv.y * Mreg[e4 * 4 + 1]
                       + wv.z * Mreg[e4 * 4 + 2] + wv.w * Mreg[e4 * 4 + 3];
                }
                W2T[((size_t)b * DIMM + ob + o) * DIMM + h * 64 + d] = (u16t)bfc(a);
            }
        }
    }
}

// ---------------------------------------------------------------------------
// out GEMM (R6-proven): Out[4096x512](f32) = V[4096x512](bf16, stride 1536)
//           @ W2T_b[512x512]^T(bf16) + bias. GLL + dbuf + 1 barrier/K-step.
// ---------------------------------------------------------------------------
__device__ inline void gll16(const u16t* gp, void* lp) {
    __builtin_amdgcn_global_load_lds(
        (const __attribute__((address_space(1))) void*)gp,
        (__attribute__((address_space(3))) void*)lp,
        16, 0, 0);
}

__global__ __launch_bounds__(256) void outgemm(
    const u16t* __restrict__ Aq, const u16t* __restrict__ W2T,
    const float* __restrict__ bias, float* __restrict__ Out)
{
    __shared__ __align__(16) char smem[24576];   // buf: 12KB = A 8KB + B 4KB

    const int tid  = threadIdx.x;
    const int wave = tid >> 6, lane = tid & 63;
    const int wr = wave >> 1, wc = wave & 1;

    int bid = blockIdx.y * gridDim.x + blockIdx.x;   // 32x8 = 256
    int swz = (bid & 7) * 32 + (bid >> 3);
    const int row0 = (swz & 31) * 128;
    const int c0   = (swz >> 5) * 64;
    const u16t* Bp = W2T + (size_t)(row0 >> 11) * (DIMM * DIMM);

    size_t gA[2], gB;
#pragma unroll
    for (int j = 0; j < 2; ++j) {
        int c = wave * 2 + j;
        int gi = SWZ((c * 64 + lane) * 16) >> 4;
        int row = gi >> 2, col = (gi & 3) * 8;
        gA[j] = (size_t)(row0 + row) * NC3 + col;
    }
    {
        int gi = SWZ((wave * 64 + lane) * 16) >> 4;
        int row = gi >> 2, col = (gi & 3) * 8;
        gB = (size_t)(c0 + row) * DIMM + col;
    }

    int rdA[4], rdB[2];
#pragma unroll
    for (int i = 0; i < 4; ++i) {
        int Pa = (wr * 64 + i * 16 + (lane & 15)) * 64 + (lane >> 4) * 16;
        rdA[i] = SWZ(Pa);
    }
#pragma unroll
    for (int j = 0; j < 2; ++j) {
        int Pb = (wc * 32 + j * 16 + (lane & 15)) * 64 + (lane >> 4) * 16;
        rdB[j] = 8192 + SWZ(Pb);
    }

#define OSTAGE(BUF, KT) {                                                     \
    char* sb = smem + (BUF) * 12288;                                          \
    _Pragma("unroll")                                                         \
    for (int j = 0; j < 2; ++j)                                               \
        gll16(Aq + gA[j] + (KT), sb + (wave * 2 + j) * 1024);                 \
    gll16(Bp + gB + (KT), sb + 8192 + wave * 1024);                           \
    }

    f32x4 acc[4][2];
#pragma unroll
    for (int i = 0; i < 4; ++i)
#pragma unroll
        for (int j = 0; j < 2; ++j) acc[i][j] = (f32x4){0.f, 0.f, 0.f, 0.f};

    OSTAGE(0, 0);
    for (int t = 0; t < 16; ++t) {
        __syncthreads();
        if (t < 15) OSTAGE((t + 1) & 1, (t + 1) * 32);
        const char* rb = smem + (t & 1) * 12288;
        short8 af[4], bfr[2];
#pragma unroll
        for (int i = 0; i < 4; ++i) af[i]  = *(const short8*)(rb + rdA[i]);
#pragma unroll
        for (int j = 0; j < 2; ++j) bfr[j] = *(const short8*)(rb + rdB[j]);
#pragma unroll
        for (int i = 0; i < 4; ++i)
#pragma unroll
            for (int j = 0; j < 2; ++j)
                acc[i][j] = __builtin_amdgcn_mfma_f32_16x16x32_bf16(
                    af[i], bfr[j], acc[i][j], 0, 0, 0);
    }
#undef OSTAGE

#pragma unroll
    for (int j = 0; j < 2; ++j) {
        int col = c0 + wc * 32 + j * 16 + (lane & 15);
        float bb = bias[col];
#pragma unroll
        for (int i = 0; i < 4; ++i) {
#pragma unroll
            for (int r = 0; r < 4; ++r) {
                int row = row0 + wr * 64 + i * 16 + (lane >> 4) * 4 + r;
                Out[(size_t)row * DIMM + col] = acc[i][j][r] + bb;
            }
        }
    }
}

// ---------------------------------------------------------------------------
extern "C" void kernel_launch(void* const* d_in, const int* in_sizes, int n_in,
                              void* d_out, int out_size, void* d_ws, size_t ws_size,
                              hipStream_t stream)
{
    const float* x     = (const float*)d_in[0];   // (2,2048,512)
    const float* w_qkv = (const float*)d_in[1];   // (1536,512)
    const float* w_out = (const float*)d_in[2];   // (512,512)
    const float* b_out = (const float*)d_in[3];   // (512,)
    float* out = (float*)d_out;                   // (2,2048,512)

    char* w = (char*)d_ws;
    u16t*     QKV  = (u16t*)    (w);              // 12,582,912 B
    float*    Mp   = (float*)   (w + 12582912);   //  8,388,608 B
    float*    ksum = (float*)   (w + 20971520);   //    131,072 B
    u16t*     W2T  = (u16t*)    (w + 21102592);   //  1,048,576 B
    unsigned* ctr  = (unsigned*)(w + 22151168);   //         64 B (end ~22.2 MB)

    // 1) qkv projection (fused fp32->bf16 staging) -> bf16 QKV [4096][1536];
    //    also resets the producer/consumer counters.
    qkvgemm<<<dim3(32, 12), 256, 0, stream>>>(x, w_qkv, QKV, ctr);

    // 2) fused: partial M + k-softmax denoms (512 blocks) -> per-bh spin ->
    //    reduce + normalize + fold into w_out -> W2T (64 blocks)
    mpartf<<<dim3(576), 256, 0, stream>>>(QKV, Mp, ksum, w_out, W2T, ctr);

    // 3) out = V @ W2T^T + bias
    outgemm<<<dim3(32, 8), 256, 0, stream>>>(QKV + 1024, W2T, b_out, out);
}

// Round 8
// 65.275 us; speedup vs baseline: 1.3492x; 1.3492x over previous
//
#include <hip/hip_runtime.h>
#include <hip/hip_bf16.h>
#include <math.h>

// Problem constants
#define BB   2
#define NN   2048
#define DIMM 512
#define HH   8
#define NC3  1536
#define BN   4096

typedef __attribute__((ext_vector_type(8))) short short8;
typedef __attribute__((ext_vector_type(4))) float f32x4;
typedef unsigned short u16t;

__device__ inline short bfc(float f) {
    __hip_bfloat16 h = __float2bfloat16(f);
    return *reinterpret_cast<short*>(&h);
}
__device__ inline float bf2f(u16t u) {
    return __uint_as_float(((unsigned)u) << 16);
}

// XOR-swizzle of 16B granules within [rows x 64B] LDS tiles (involution,
// applied on BOTH ds_write and ds_read sides — R3-proven mapping).
#define SWZ(P) ((P) ^ ((((P) >> 7) & 3) << 4))

// ---------------------------------------------------------------------------
// qkv GEMM (proven): QKV[4096x1536](bf16) = x[4096x512](f32) @ w_qkv^T(f32)
// fp32->bf16 conversion fused into staging. 128x128 tile, BK=32, 4 waves 2x2.
// ---------------------------------------------------------------------------
__global__ __launch_bounds__(256) void qkvgemm(
    const float* __restrict__ A, const float* __restrict__ Bw,
    u16t* __restrict__ QKV)
{
    __shared__ __align__(16) char smem[16384];   // A [0,8K), B [8K,16K)

    const int tid  = threadIdx.x;
    const int wave = tid >> 6, lane = tid & 63;
    const int wr = wave >> 1, wc = wave & 1;

    // XCD-aware bijective swizzle (nwg = 384, 384/8 = 48)
    int bid = blockIdx.y * gridDim.x + blockIdx.x;
    int swz = (bid & 7) * 48 + (bid >> 3);
    const int row0 = (swz & 31) * 128;           // gridDim.x == 32
    const int c0   = (swz >> 5) * 128;

    float4 ra[2][2], rb[2][2];

#define QLOAD(KT) {                                                           \
    _Pragma("unroll")                                                         \
    for (int it = 0; it < 2; ++it) {                                          \
        int c = tid + it * 256, r = c >> 2, g = c & 3;                        \
        const float* pa = A + (size_t)(row0 + r) * DIMM + (KT) + g * 8;       \
        ra[it][0] = *(const float4*)pa; ra[it][1] = *(const float4*)(pa + 4); \
        const float* pb = Bw + (size_t)(c0 + r) * DIMM + (KT) + g * 8;        \
        rb[it][0] = *(const float4*)pb; rb[it][1] = *(const float4*)(pb + 4); \
    } }

#define QWRITE() {                                                            \
    _Pragma("unroll")                                                         \
    for (int it = 0; it < 2; ++it) {                                          \
        int P = (tid + it * 256) * 16;                                        \
        short8 av, bv;                                                        \
        av[0]=bfc(ra[it][0].x); av[1]=bfc(ra[it][0].y);                       \
        av[2]=bfc(ra[it][0].z); av[3]=bfc(ra[it][0].w);                       \
        av[4]=bfc(ra[it][1].x); av[5]=bfc(ra[it][1].y);                       \
        av[6]=bfc(ra[it][1].z); av[7]=bfc(ra[it][1].w);                       \
        bv[0]=bfc(rb[it][0].x); bv[1]=bfc(rb[it][0].y);                       \
        bv[2]=bfc(rb[it][0].z); bv[3]=bfc(rb[it][0].w);                       \
        bv[4]=bfc(rb[it][1].x); bv[5]=bfc(rb[it][1].y);                       \
        bv[6]=bfc(rb[it][1].z); bv[7]=bfc(rb[it][1].w);                       \
        *(short8*)(smem + SWZ(P)) = av;                                       \
        *(short8*)(smem + 8192 + SWZ(P)) = bv;                                \
    } }

    int rdA[4], rdB[4];
#pragma unroll
    for (int i = 0; i < 4; ++i) {
        int Pa = (wr * 64 + i * 16 + (lane & 15)) * 64 + (lane >> 4) * 16;
        rdA[i] = SWZ(Pa);
        int Pb = (wc * 64 + i * 16 + (lane & 15)) * 64 + (lane >> 4) * 16;
        rdB[i] = 8192 + SWZ(Pb);
    }

    f32x4 acc[4][4];
#pragma unroll
    for (int i = 0; i < 4; ++i)
#pragma unroll
        for (int j = 0; j < 4; ++j) acc[i][j] = (f32x4){0.f, 0.f, 0.f, 0.f};

    QLOAD(0);
    for (int kt = 0; kt < DIMM; kt += 32) {
        QWRITE();
        __syncthreads();
        if (kt + 32 < DIMM) QLOAD(kt + 32);

        short8 af[4], bfr[4];
#pragma unroll
        for (int i = 0; i < 4; ++i) {
            af[i]  = *(const short8*)(smem + rdA[i]);
            bfr[i] = *(const short8*)(smem + rdB[i]);
        }
#pragma unroll
        for (int i = 0; i < 4; ++i)
#pragma unroll
            for (int j = 0; j < 4; ++j)
                acc[i][j] = __builtin_amdgcn_mfma_f32_16x16x32_bf16(
                    af[i], bfr[j], acc[i][j], 0, 0, 0);
        __syncthreads();
    }
#undef QLOAD
#undef QWRITE

#pragma unroll
    for (int j = 0; j < 4; ++j) {
        int col = c0 + wc * 64 + j * 16 + (lane & 15);
#pragma unroll
        for (int i = 0; i < 4; ++i) {
#pragma unroll
            for (int r = 0; r < 4; ++r) {
                int row = row0 + wr * 64 + i * 16 + (lane >> 4) * 4 + r;
                QKV[(size_t)row * NC3 + col] = (u16t)bfc(acc[i][j][r]);
            }
        }
    }
}

// ---------------------------------------------------------------------------
// mpart (MFMA rebuild): per (bh, chunk of 256 rows):
//   phase 1: qs[i][e] = softmax_e(Q[i]) (no-max, R7-proven), ks[i][d]=exp(K)
//            written TRANSPOSED as bf16 LDS tiles qsT/ksT [64 dims][264]
//   phase 2: per wave: 64x64 M-partial over its 64-row K-slice via
//            mfma_f32_16x16x32_bf16 (C = ksT · qsT^T over seq)
//   phase 3: LDS-reduce 4 wave partials -> Mp[bh*8+ch] (16KB f32); ksum.
// grid (16, 8) x 256. LDS 67.6KB -> 2 blocks/CU.
// ---------------------------------------------------------------------------
#define TSTR 264   // bf16 elements per d-row (256 + 8 pad)

__global__ __launch_bounds__(256) void mpart(
    const u16t* __restrict__ QKV, float* __restrict__ Mp, float* __restrict__ ksump)
{
    __shared__ __align__(16) char sh[67584];
    u16t* ksT = (u16t*)sh;                    // [64][264] bf16 = 33792 B
    u16t* qsT = (u16t*)(sh + 33792);          // [64][264] bf16 = 33792 B
    float* scratch = (float*)sh;              // reduce reuse: 4 x 4096 f32 = 64KB

    const int bh = blockIdx.x, ch = blockIdx.y;
    const int b = bh >> 3, h = bh & 7;
    const int tid = threadIdx.x;
    const u16t* base = QKV + ((size_t)b * NN + ch * 256) * NC3 + h * 64;

    const int rl0 = tid >> 3;          // row within pass: 0..31
    const int d0  = (tid & 7) * 8;     // dim octet

    // ---- phase 1: softmax + exp + transpose to LDS (bf16)
    for (int pass = 0; pass < 8; ++pass) {
        int r = pass * 32 + rl0;
        const u16t* rowp = base + (size_t)r * NC3 + d0;
        short8 qv = *(const short8*)(rowp);
        short8 kv = *(const short8*)(rowp + 512);
        float e[8]; float s = 0.f;
#pragma unroll
        for (int u = 0; u < 8; ++u) { e[u] = __expf(bf2f((u16t)qv[u])); s += e[u]; }
        s += __shfl_xor(s, 1); s += __shfl_xor(s, 2); s += __shfl_xor(s, 4);
        float inv = 1.0f / s;
#pragma unroll
        for (int u = 0; u < 8; ++u)
            qsT[(d0 + u) * TSTR + r] = (u16t)bfc(e[u] * inv);
#pragma unroll
        for (int u = 0; u < 8; ++u)
            ksT[(d0 + u) * TSTR + r] = (u16t)bfc(__expf(bf2f((u16t)kv[u])));
    }
    __syncthreads();

    // ---- ksum per d (from the SAME rounded bf16 ks used by MFMA)
    float kss = 0.f;
    if (tid < 64) {
        const u16t* rowk = ksT + tid * TSTR;
#pragma unroll
        for (int i = 0; i < 256; i += 8) {
            short8 v = *(const short8*)(rowk + i);
#pragma unroll
            for (int u = 0; u < 8; ++u) kss += bf2f((u16t)v[u]);
        }
    }

    // ---- phase 2: MFMA. wave w covers seq slice [w*64, w*64+64)
    const int wave = tid >> 6, lane = tid & 63;
    f32x4 acc[4][4];
#pragma unroll
    for (int i = 0; i < 4; ++i)
#pragma unroll
        for (int j = 0; j < 4; ++j) acc[i][j] = (f32x4){0.f, 0.f, 0.f, 0.f};

#pragma unroll
    for (int ks2 = 0; ks2 < 2; ++ks2) {
        int kb = wave * 64 + ks2 * 32 + (lane >> 4) * 8;
        short8 af[4], bfr[4];
#pragma unroll
        for (int i = 0; i < 4; ++i) {
            af[i]  = *(const short8*)(ksT + (i * 16 + (lane & 15)) * TSTR + kb);
            bfr[i] = *(const short8*)(qsT + (i * 16 + (lane & 15)) * TSTR + kb);
        }
#pragma unroll
        for (int i = 0; i < 4; ++i)
#pragma unroll
            for (int j = 0; j < 4; ++j)
                acc[i][j] = __builtin_amdgcn_mfma_f32_16x16x32_bf16(
                    af[i], bfr[j], acc[i][j], 0, 0, 0);
    }
    __syncthreads();   // all LDS reads (incl. ksum) done before scratch reuse

    // ---- phase 3: write wave partials, reduce, store
    {
        float* sw = scratch + wave * 4096;
#pragma unroll
        for (int i = 0; i < 4; ++i)
#pragma unroll
            for (int j = 0; j < 4; ++j)
#pragma unroll
                for (int r4 = 0; r4 < 4; ++r4) {
                    int d = i * 16 + (lane >> 4) * 4 + r4;
                    int e = j * 16 + (lane & 15);
                    sw[d * 64 + e] = acc[i][j][r4];
                }
    }
    __syncthreads();

    float* mp = Mp + ((size_t)(bh * 8 + ch)) * 4096;
    for (int q = 0; q < 16; ++q) {
        int idx = q * 256 + tid;
        mp[idx] = scratch[idx] + scratch[4096 + idx]
                + scratch[8192 + idx] + scratch[12288 + idx];
    }
    if (tid < 64) ksump[(bh * 8 + ch) * 64 + tid] = kss;
}

// ---------------------------------------------------------------------------
// mfinal (proven): reduce Mp (8 chunks) -> M, fold into w_out -> W2T (bf16)
// grid (16 bh, 4 o-tiles of 128), block 256.
// ---------------------------------------------------------------------------
__global__ __launch_bounds__(256) void mfinal(
    const float* __restrict__ Mp, const float* __restrict__ ksump,
    const float* __restrict__ w_out, u16t* __restrict__ W2T)
{
    __shared__ float kst[64];
    __shared__ float Ms[64][68];
    __shared__ float Wt[64][64];

    int bh = blockIdx.x, ot = blockIdx.y;
    int b = bh >> 3, h = bh & 7;
    int tid = threadIdx.x;
    int d = tid & 63, og = tid >> 6;

    if (tid < 64) {
        float s = 0.f;
        for (int c = 0; c < 8; ++c) s += ksump[(bh * 8 + c) * 64 + tid];
        kst[tid] = s;
    }
    __syncthreads();

    for (int idx = tid; idx < 4096; idx += 256) {
        float s = 0.f;
        for (int c = 0; c < 8; ++c)
            s += Mp[((size_t)(bh * 8 + c)) * 4096 + idx];
        Ms[idx >> 6][idx & 63] = s / kst[idx >> 6];
    }
    __syncthreads();

    float Mreg[64];
#pragma unroll
    for (int e4 = 0; e4 < 16; ++e4) {
        float4 v = *(const float4*)&Ms[d][e4 * 4];
        Mreg[e4 * 4 + 0] = v.x; Mreg[e4 * 4 + 1] = v.y;
        Mreg[e4 * 4 + 2] = v.z; Mreg[e4 * 4 + 3] = v.w;
    }

    for (int sub = 0; sub < 2; ++sub) {
        int ob = ot * 128 + sub * 64;
        __syncthreads();
        {
            int o = tid >> 2, e0 = (tid & 3) * 16;
#pragma unroll
            for (int q = 0; q < 4; ++q)
                *(float4*)&Wt[o][e0 + q * 4] =
                    *(const float4*)&w_out[(size_t)(ob + o) * DIMM + h * 64 + e0 + q * 4];
        }
        __syncthreads();
#pragma unroll
        for (int oo = 0; oo < 16; ++oo) {
            int o = og * 16 + oo;
            float a = 0.f;
#pragma unroll
            for (int e4 = 0; e4 < 16; ++e4) {
                float4 wv = *(const float4*)&Wt[o][e4 * 4];
                a += wv.x * Mreg[e4 * 4 + 0] + wv.y * Mreg[e4 * 4 + 1]
                   + wv.z * Mreg[e4 * 4 + 2] + wv.w * Mreg[e4 * 4 + 3];
            }
            W2T[((size_t)b * DIMM + ob + o) * DIMM + h * 64 + d] = (u16t)bfc(a);
        }
    }
}

// ---------------------------------------------------------------------------
// out GEMM (proven): Out[4096x512](f32) = V[4096x512](bf16, stride 1536)
//           @ W2T_b[512x512]^T(bf16) + bias. GLL + dbuf + 1 barrier/K-step.
// ---------------------------------------------------------------------------
__device__ inline void gll16(const u16t* gp, void* lp) {
    __builtin_amdgcn_global_load_lds(
        (const __attribute__((address_space(1))) void*)gp,
        (__attribute__((address_space(3))) void*)lp,
        16, 0, 0);
}

__global__ __launch_bounds__(256) void outgemm(
    const u16t* __restrict__ Aq, const u16t* __restrict__ W2T,
    const float* __restrict__ bias, float* __restrict__ Out)
{
    __shared__ __align__(16) char smem[24576];   // buf: 12KB = A 8KB + B 4KB

    const int tid  = threadIdx.x;
    const int wave = tid >> 6, lane = tid & 63;
    const int wr = wave >> 1, wc = wave & 1;

    int bid = blockIdx.y * gridDim.x + blockIdx.x;   // 32x8 = 256
    int swz = (bid & 7) * 32 + (bid >> 3);
    const int row0 = (swz & 31) * 128;
    const int c0   = (swz >> 5) * 64;
    const u16t* Bp = W2T + (size_t)(row0 >> 11) * (DIMM * DIMM);

    size_t gA[2], gB;
#pragma unroll
    for (int j = 0; j < 2; ++j) {
        int c = wave * 2 + j;
        int gi = SWZ((c * 64 + lane) * 16) >> 4;
        int row = gi >> 2, col = (gi & 3) * 8;
        gA[j] = (size_t)(row0 + row) * NC3 + col;
    }
    {
        int gi = SWZ((wave * 64 + lane) * 16) >> 4;
        int row = gi >> 2, col = (gi & 3) * 8;
        gB = (size_t)(c0 + row) * DIMM + col;
    }

    int rdA[4], rdB[2];
#pragma unroll
    for (int i = 0; i < 4; ++i) {
        int Pa = (wr * 64 + i * 16 + (lane & 15)) * 64 + (lane >> 4) * 16;
        rdA[i] = SWZ(Pa);
    }
#pragma unroll
    for (int j = 0; j < 2; ++j) {
        int Pb = (wc * 32 + j * 16 + (lane & 15)) * 64 + (lane >> 4) * 16;
        rdB[j] = 8192 + SWZ(Pb);
    }

#define OSTAGE(BUF, KT) {                                                     \
    char* sb = smem + (BUF) * 12288;                                          \
    _Pragma("unroll")                                                         \
    for (int j = 0; j < 2; ++j)                                               \
        gll16(Aq + gA[j] + (KT), sb + (wave * 2 + j) * 1024);                 \
    gll16(Bp + gB + (KT), sb + 8192 + wave * 1024);                           \
    }

    f32x4 acc[4][2];
#pragma unroll
    for (int i = 0; i < 4; ++i)
#pragma unroll
        for (int j = 0; j < 2; ++j) acc[i][j] = (f32x4){0.f, 0.f, 0.f, 0.f};

    OSTAGE(0, 0);
    for (int t = 0; t < 16; ++t) {
        __syncthreads();
        if (t < 15) OSTAGE((t + 1) & 1, (t + 1) * 32);
        const char* rb = smem + (t & 1) * 12288;
        short8 af[4], bfr[2];
#pragma unroll
        for (int i = 0; i < 4; ++i) af[i]  = *(const short8*)(rb + rdA[i]);
#pragma unroll
        for (int j = 0; j < 2; ++j) bfr[j] = *(const short8*)(rb + rdB[j]);
#pragma unroll
        for (int i = 0; i < 4; ++i)
#pragma unroll
            for (int j = 0; j < 2; ++j)
                acc[i][j] = __builtin_amdgcn_mfma_f32_16x16x32_bf16(
                    af[i], bfr[j], acc[i][j], 0, 0, 0);
    }
#undef OSTAGE

#pragma unroll
    for (int j = 0; j < 2; ++j) {
        int col = c0 + wc * 32 + j * 16 + (lane & 15);
        float bb = bias[col];
#pragma unroll
        for (int i = 0; i < 4; ++i) {
#pragma unroll
            for (int r = 0; r < 4; ++r) {
                int row = row0 + wr * 64 + i * 16 + (lane >> 4) * 4 + r;
                Out[(size_t)row * DIMM + col] = acc[i][j][r] + bb;
            }
        }
    }
}

// ---------------------------------------------------------------------------
extern "C" void kernel_launch(void* const* d_in, const int* in_sizes, int n_in,
                              void* d_out, int out_size, void* d_ws, size_t ws_size,
                              hipStream_t stream)
{
    const float* x     = (const float*)d_in[0];   // (2,2048,512)
    const float* w_qkv = (const float*)d_in[1];   // (1536,512)
    const float* w_out = (const float*)d_in[2];   // (512,512)
    const float* b_out = (const float*)d_in[3];   // (512,)
    float* out = (float*)d_out;                   // (2,2048,512)

    char* w = (char*)d_ws;
    u16t*  QKV  = (u16t*) (w);              // 12,582,912 B
    float* Mp   = (float*)(w + 12582912);   //  2,097,152 B
    float* ksum = (float*)(w + 14680064);   //     32,768 B
    u16t*  W2T  = (u16t*) (w + 14712832);   //  1,048,576 B  (end ~15.8 MB)

    // 1) qkv projection (fused fp32->bf16 staging) -> bf16 QKV [4096][1536]
    qkvgemm<<<dim3(32, 12), 256, 0, stream>>>(x, w_qkv, QKV);

    // 2) M partials via MFMA (16 bh x 8 chunks of 256 rows)
    mpart<<<dim3(16, 8), 256, 0, stream>>>(QKV, Mp, ksum);

    // 3) reduce partials + normalize + fold into w_out -> W2T (bf16)
    mfinal<<<dim3(16, 4), 256, 0, stream>>>(Mp, ksum, w_out, W2T);

    // 4) out = V @ W2T^T + bias
    outgemm<<<dim3(32, 8), 256, 0, stream>>>(QKV + 1024, W2T, b_out, out);
}

// Round 9
// 63.559 us; speedup vs baseline: 1.3856x; 1.0270x over previous
//
#include <hip/hip_runtime.h>
#include <hip/hip_bf16.h>
#include <math.h>

// Problem constants
#define BB   2
#define NN   2048
#define DIMM 512
#define HH   8
#define NC3  1536
#define BN   4096

typedef __attribute__((ext_vector_type(8))) short short8;
typedef __attribute__((ext_vector_type(4))) float f32x4;
typedef unsigned short u16t;

__device__ inline short bfc(float f) {
    __hip_bfloat16 h = __float2bfloat16(f);
    return *reinterpret_cast<short*>(&h);
}
__device__ inline float bf2f(u16t u) {
    return __uint_as_float(((unsigned)u) << 16);
}

// XOR-swizzle of 16B granules within [rows x 64B] LDS tiles (involution,
// applied on BOTH ds_write and ds_read sides — R3-proven mapping).
#define SWZ(P) ((P) ^ ((((P) >> 7) & 3) << 4))

// ---------------------------------------------------------------------------
// qkv GEMM (proven): QKV[4096x1536](bf16) = x[4096x512](f32) @ w_qkv^T(f32)
// fp32->bf16 conversion fused into staging. 128x128 tile, BK=32, 4 waves 2x2.
// ---------------------------------------------------------------------------
__global__ __launch_bounds__(256) void qkvgemm(
    const float* __restrict__ A, const float* __restrict__ Bw,
    u16t* __restrict__ QKV)
{
    __shared__ __align__(16) char smem[16384];   // A [0,8K), B [8K,16K)

    const int tid  = threadIdx.x;
    const int wave = tid >> 6, lane = tid & 63;
    const int wr = wave >> 1, wc = wave & 1;

    // XCD-aware bijective swizzle (nwg = 384, 384/8 = 48)
    int bid = blockIdx.y * gridDim.x + blockIdx.x;
    int swz = (bid & 7) * 48 + (bid >> 3);
    const int row0 = (swz & 31) * 128;           // gridDim.x == 32
    const int c0   = (swz >> 5) * 128;

    float4 ra[2][2], rb[2][2];

#define QLOAD(KT) {                                                           \
    _Pragma("unroll")                                                         \
    for (int it = 0; it < 2; ++it) {                                          \
        int c = tid + it * 256, r = c >> 2, g = c & 3;                        \
        const float* pa = A + (size_t)(row0 + r) * DIMM + (KT) + g * 8;       \
        ra[it][0] = *(const float4*)pa; ra[it][1] = *(const float4*)(pa + 4); \
        const float* pb = Bw + (size_t)(c0 + r) * DIMM + (KT) + g * 8;        \
        rb[it][0] = *(const float4*)pb; rb[it][1] = *(const float4*)(pb + 4); \
    } }

#define QWRITE() {                                                            \
    _Pragma("unroll")                                                         \
    for (int it = 0; it < 2; ++it) {                                          \
        int P = (tid + it * 256) * 16;                                        \
        short8 av, bv;                                                        \
        av[0]=bfc(ra[it][0].x); av[1]=bfc(ra[it][0].y);                       \
        av[2]=bfc(ra[it][0].z); av[3]=bfc(ra[it][0].w);                       \
        av[4]=bfc(ra[it][1].x); av[5]=bfc(ra[it][1].y);                       \
        av[6]=bfc(ra[it][1].z); av[7]=bfc(ra[it][1].w);                       \
        bv[0]=bfc(rb[it][0].x); bv[1]=bfc(rb[it][0].y);                       \
        bv[2]=bfc(rb[it][0].z); bv[3]=bfc(rb[it][0].w);                       \
        bv[4]=bfc(rb[it][1].x); bv[5]=bfc(rb[it][1].y);                       \
        bv[6]=bfc(rb[it][1].z); bv[7]=bfc(rb[it][1].w);                       \
        *(short8*)(smem + SWZ(P)) = av;                                       \
        *(short8*)(smem + 8192 + SWZ(P)) = bv;                                \
    } }

    int rdA[4], rdB[4];
#pragma unroll
    for (int i = 0; i < 4; ++i) {
        int Pa = (wr * 64 + i * 16 + (lane & 15)) * 64 + (lane >> 4) * 16;
        rdA[i] = SWZ(Pa);
        int Pb = (wc * 64 + i * 16 + (lane & 15)) * 64 + (lane >> 4) * 16;
        rdB[i] = 8192 + SWZ(Pb);
    }

    f32x4 acc[4][4];
#pragma unroll
    for (int i = 0; i < 4; ++i)
#pragma unroll
        for (int j = 0; j < 4; ++j) acc[i][j] = (f32x4){0.f, 0.f, 0.f, 0.f};

    QLOAD(0);
    for (int kt = 0; kt < DIMM; kt += 32) {
        QWRITE();
        __syncthreads();
        if (kt + 32 < DIMM) QLOAD(kt + 32);

        short8 af[4], bfr[4];
#pragma unroll
        for (int i = 0; i < 4; ++i) {
            af[i]  = *(const short8*)(smem + rdA[i]);
            bfr[i] = *(const short8*)(smem + rdB[i]);
        }
#pragma unroll
        for (int i = 0; i < 4; ++i)
#pragma unroll
            for (int j = 0; j < 4; ++j)
                acc[i][j] = __builtin_amdgcn_mfma_f32_16x16x32_bf16(
                    af[i], bfr[j], acc[i][j], 0, 0, 0);
        __syncthreads();
    }
#undef QLOAD
#undef QWRITE

#pragma unroll
    for (int j = 0; j < 4; ++j) {
        int col = c0 + wc * 64 + j * 16 + (lane & 15);
#pragma unroll
        for (int i = 0; i < 4; ++i) {
#pragma unroll
            for (int r = 0; r < 4; ++r) {
                int row = row0 + wr * 64 + i * 16 + (lane >> 4) * 4 + r;
                QKV[(size_t)row * NC3 + col] = (u16t)bfc(acc[i][j][r]);
            }
        }
    }
}

// ---------------------------------------------------------------------------
// mpart (occupancy rebuild): grid (16 bh, 16 chunks of 128 rows) x 512 thr.
//   phase 1: qs = softmax_e(Q) (no-max), ks = exp(K); stored transposed bf16
//     in [64 d][136] tiles with 16B-granule index XOR'd by (d>>3):
//     element (d, i) lives at d*136 + ((i>>3)^(d>>3))*8 + (i&7).
//     -> scattered b16 writes are 2 lanes/bank (free); MFMA reads contiguous.
//   phase 2: 8 waves = 4 d-groups x 2 i-halves; each wave accumulates its
//     16x64 M-partial via mfma_16x16x32 and stores straight to global Mp.
//   ksum per d from the SAME rounded bf16 ks.
// LDS 34.8KB. No intra-block reduce, no extra barrier.
// ---------------------------------------------------------------------------
#define TST 136   // shorts per d-row (17 granules of 8)

__global__ __launch_bounds__(512) void mpart(
    const u16t* __restrict__ QKV, float* __restrict__ Mp, float* __restrict__ ksump)
{
    __shared__ __align__(16) char sh[34816];
    u16t* ksT = (u16t*)sh;                    // [64][136]
    u16t* qsT = (u16t*)(sh + 17408);          // [64][136]

    const int bh = blockIdx.x, ch = blockIdx.y;
    const int b = bh >> 3, h = bh & 7;
    const int tid = threadIdx.x;
    const u16t* base = QKV + ((size_t)b * NN + ch * 128) * NC3 + h * 64;

    const int k7 = tid & 7;           // d-octet id
    const int d0 = k7 * 8;
    const int rr = tid >> 3;          // 0..63

    // ---- phase 1
#pragma unroll
    for (int pass = 0; pass < 2; ++pass) {
        int r = pass * 64 + rr;
        const u16t* rowp = base + (size_t)r * NC3 + d0;
        short8 qv = *(const short8*)(rowp);
        short8 kv = *(const short8*)(rowp + 512);
        float e[8]; float s = 0.f;
#pragma unroll
        for (int u = 0; u < 8; ++u) { e[u] = __expf(bf2f((u16t)qv[u])); s += e[u]; }
        s += __shfl_xor(s, 1); s += __shfl_xor(s, 2); s += __shfl_xor(s, 4);
        float inv = 1.0f / s;
        int gx = ((r >> 3) ^ k7) * 8 + (r & 7);   // (d0+u)>>3 == k7 for u<8
#pragma unroll
        for (int u = 0; u < 8; ++u)
            qsT[(d0 + u) * TST + gx] = (u16t)bfc(e[u] * inv);
#pragma unroll
        for (int u = 0; u < 8; ++u)
            ksT[(d0 + u) * TST + gx] = (u16t)bfc(__expf(bf2f((u16t)kv[u])));
    }
    __syncthreads();

    // ---- ksum (wave 0 lanes; from the rounded bf16 ks)
    if (tid < 64) {
        float kss = 0.f;
#pragma unroll
        for (int gg = 0; gg < 16; ++gg) {
            short8 v = *(const short8*)(ksT + tid * TST + gg * 8);
#pragma unroll
            for (int u = 0; u < 8; ++u) kss += bf2f((u16t)v[u]);
        }
        ksump[(bh * 16 + ch) * 64 + tid] = kss;
    }

    // ---- phase 2: wave = (d-group g, i-half kh)
    const int wave = tid >> 6, lane = tid & 63;
    const int g = wave >> 1, kh = wave & 1;
    const int dl = lane & 15, kq = lane >> 4;
    const int d = g * 16 + dl;

    f32x4 acc[4];
#pragma unroll
    for (int j = 0; j < 4; ++j) acc[j] = (f32x4){0.f, 0.f, 0.f, 0.f};

#pragma unroll
    for (int ks2 = 0; ks2 < 2; ++ks2) {
        int kb = kh * 64 + ks2 * 32 + kq * 8;    // i-base (shorts)
        short8 af = *(const short8*)(ksT + d * TST + ((((kb >> 3) ^ (d >> 3))) << 3));
#pragma unroll
        for (int j = 0; j < 4; ++j) {
            int e = j * 16 + dl;
            short8 bfrj = *(const short8*)(qsT + e * TST + ((((kb >> 3) ^ (e >> 3))) << 3));
            acc[j] = __builtin_amdgcn_mfma_f32_16x16x32_bf16(af, bfrj, acc[j], 0, 0, 0);
        }
    }

    // ---- store per-wave partial: D row = g*16 + kq*4 + r, col = j*16 + dl
    float* mp = Mp + ((size_t)((bh * 16 + ch) * 2 + kh)) * 4096;
#pragma unroll
    for (int j = 0; j < 4; ++j)
#pragma unroll
        for (int r = 0; r < 4; ++r)
            mp[(g * 16 + kq * 4 + r) * 64 + j * 16 + dl] = acc[j][r];
}

// ---------------------------------------------------------------------------
// mfinal: reduce Mp (32 slices) -> M (normalized), fold into w_out -> W2T.
// grid (16 bh, 4 o-tiles of 128), block 256.
// ---------------------------------------------------------------------------
__global__ __launch_bounds__(256) void mfinal(
    const float* __restrict__ Mp, const float* __restrict__ ksump,
    const float* __restrict__ w_out, u16t* __restrict__ W2T)
{
    __shared__ float kst[64];
    __shared__ float Ms[64][68];
    __shared__ float Wt[64][64];

    int bh = blockIdx.x, ot = blockIdx.y;
    int b = bh >> 3, h = bh & 7;
    int tid = threadIdx.x;
    int d = tid & 63, og = tid >> 6;

    if (tid < 64) {
        float s = 0.f;
        for (int c = 0; c < 16; ++c) s += ksump[(bh * 16 + c) * 64 + tid];
        kst[tid] = s;
    }
    __syncthreads();

    for (int idx = tid; idx < 4096; idx += 256) {
        float s = 0.f;
        for (int c = 0; c < 32; ++c)
            s += Mp[((size_t)(bh * 32 + c)) * 4096 + idx];
        Ms[idx >> 6][idx & 63] = s / kst[idx >> 6];
    }
    __syncthreads();

    float Mreg[64];
#pragma unroll
    for (int e4 = 0; e4 < 16; ++e4) {
        float4 v = *(const float4*)&Ms[d][e4 * 4];
        Mreg[e4 * 4 + 0] = v.x; Mreg[e4 * 4 + 1] = v.y;
        Mreg[e4 * 4 + 2] = v.z; Mreg[e4 * 4 + 3] = v.w;
    }

    for (int sub = 0; sub < 2; ++sub) {
        int ob = ot * 128 + sub * 64;
        __syncthreads();
        {
            int o = tid >> 2, e0 = (tid & 3) * 16;
#pragma unroll
            for (int q = 0; q < 4; ++q)
                *(float4*)&Wt[o][e0 + q * 4] =
                    *(const float4*)&w_out[(size_t)(ob + o) * DIMM + h * 64 + e0 + q * 4];
        }
        __syncthreads();
#pragma unroll
        for (int oo = 0; oo < 16; ++oo) {
            int o = og * 16 + oo;
            float a = 0.f;
#pragma unroll
            for (int e4 = 0; e4 < 16; ++e4) {
                float4 wv = *(const float4*)&Wt[o][e4 * 4];
                a += wv.x * Mreg[e4 * 4 + 0] + wv.y * Mreg[e4 * 4 + 1]
                   + wv.z * Mreg[e4 * 4 + 2] + wv.w * Mreg[e4 * 4 + 3];
            }
            W2T[((size_t)b * DIMM + ob + o) * DIMM + h * 64 + d] = (u16t)bfc(a);
        }
    }
}

// ---------------------------------------------------------------------------
// out GEMM (proven): Out[4096x512](f32) = V[4096x512](bf16, stride 1536)
//           @ W2T_b[512x512]^T(bf16) + bias. GLL + dbuf + 1 barrier/K-step.
// ---------------------------------------------------------------------------
__device__ inline void gll16(const u16t* gp, void* lp) {
    __builtin_amdgcn_global_load_lds(
        (const __attribute__((address_space(1))) void*)gp,
        (__attribute__((address_space(3))) void*)lp,
        16, 0, 0);
}

__global__ __launch_bounds__(256) void outgemm(
    const u16t* __restrict__ Aq, const u16t* __restrict__ W2T,
    const float* __restrict__ bias, float* __restrict__ Out)
{
    __shared__ __align__(16) char smem[24576];   // buf: 12KB = A 8KB + B 4KB

    const int tid  = threadIdx.x;
    const int wave = tid >> 6, lane = tid & 63;
    const int wr = wave >> 1, wc = wave & 1;

    int bid = blockIdx.y * gridDim.x + blockIdx.x;   // 32x8 = 256
    int swz = (bid & 7) * 32 + (bid >> 3);
    const int row0 = (swz & 31) * 128;
    const int c0   = (swz >> 5) * 64;
    const u16t* Bp = W2T + (size_t)(row0 >> 11) * (DIMM * DIMM);

    size_t gA[2], gB;
#pragma unroll
    for (int j = 0; j < 2; ++j) {
        int c = wave * 2 + j;
        int gi = SWZ((c * 64 + lane) * 16) >> 4;
        int row = gi >> 2, col = (gi & 3) * 8;
        gA[j] = (size_t)(row0 + row) * NC3 + col;
    }
    {
        int gi = SWZ((wave * 64 + lane) * 16) >> 4;
        int row = gi >> 2, col = (gi & 3) * 8;
        gB = (size_t)(c0 + row) * DIMM + col;
    }

    int rdA[4], rdB[2];
#pragma unroll
    for (int i = 0; i < 4; ++i) {
        int Pa = (wr * 64 + i * 16 + (lane & 15)) * 64 + (lane >> 4) * 16;
        rdA[i] = SWZ(Pa);
    }
#pragma unroll
    for (int j = 0; j < 2; ++j) {
        int Pb = (wc * 32 + j * 16 + (lane & 15)) * 64 + (lane >> 4) * 16;
        rdB[j] = 8192 + SWZ(Pb);
    }

#define OSTAGE(BUF, KT) {                                                     \
    char* sb = smem + (BUF) * 12288;                                          \
    _Pragma("unroll")                                                         \
    for (int j = 0; j < 2; ++j)                                               \
        gll16(Aq + gA[j] + (KT), sb + (wave * 2 + j) * 1024);                 \
    gll16(Bp + gB + (KT), sb + 8192 + wave * 1024);                           \
    }

    f32x4 acc[4][2];
#pragma unroll
    for (int i = 0; i < 4; ++i)
#pragma unroll
        for (int j = 0; j < 2; ++j) acc[i][j] = (f32x4){0.f, 0.f, 0.f, 0.f};

    OSTAGE(0, 0);
    for (int t = 0; t < 16; ++t) {
        __syncthreads();
        if (t < 15) OSTAGE((t + 1) & 1, (t + 1) * 32);
        const char* rb = smem + (t & 1) * 12288;
        short8 af[4], bfr[2];
#pragma unroll
        for (int i = 0; i < 4; ++i) af[i]  = *(const short8*)(rb + rdA[i]);
#pragma unroll
        for (int j = 0; j < 2; ++j) bfr[j] = *(const short8*)(rb + rdB[j]);
#pragma unroll
        for (int i = 0; i < 4; ++i)
#pragma unroll
            for (int j = 0; j < 2; ++j)
                acc[i][j] = __builtin_amdgcn_mfma_f32_16x16x32_bf16(
                    af[i], bfr[j], acc[i][j], 0, 0, 0);
    }
#undef OSTAGE

#pragma unroll
    for (int j = 0; j < 2; ++j) {
        int col = c0 + wc * 32 + j * 16 + (lane & 15);
        float bb = bias[col];
#pragma unroll
        for (int i = 0; i < 4; ++i) {
#pragma unroll
            for (int r = 0; r < 4; ++r) {
                int row = row0 + wr * 64 + i * 16 + (lane >> 4) * 4 + r;
                Out[(size_t)row * DIMM + col] = acc[i][j][r] + bb;
            }
        }
    }
}

// ---------------------------------------------------------------------------
extern "C" void kernel_launch(void* const* d_in, const int* in_sizes, int n_in,
                              void* d_out, int out_size, void* d_ws, size_t ws_size,
                              hipStream_t stream)
{
    const float* x     = (const float*)d_in[0];   // (2,2048,512)
    const float* w_qkv = (const float*)d_in[1];   // (1536,512)
    const float* w_out = (const float*)d_in[2];   // (512,512)
    const float* b_out = (const float*)d_in[3];   // (512,)
    float* out = (float*)d_out;                   // (2,2048,512)

    char* w = (char*)d_ws;
    u16t*  QKV  = (u16t*) (w);              // 12,582,912 B
    float* Mp   = (float*)(w + 12582912);   //  8,388,608 B
    float* ksum = (float*)(w + 20971520);   //     65,536 B
    u16t*  W2T  = (u16t*) (w + 21037056);   //  1,048,576 B  (end ~22.1 MB)

    // 1) qkv projection (fused fp32->bf16 staging) -> bf16 QKV [4096][1536]
    qkvgemm<<<dim3(32, 12), 256, 0, stream>>>(x, w_qkv, QKV);

    // 2) M partials via MFMA (16 bh x 16 chunks of 128 rows, 8 waves/block)
    mpart<<<dim3(16, 16), 512, 0, stream>>>(QKV, Mp, ksum);

    // 3) reduce partials + normalize + fold into w_out -> W2T (bf16)
    mfinal<<<dim3(16, 4), 256, 0, stream>>>(Mp, ksum, w_out, W2T);

    // 4) out = V @ W2T^T + bias
    outgemm<<<dim3(32, 8), 256, 0, stream>>>(QKV + 1024, W2T, b_out, out);
}